// Round 3
// baseline (208.544 us; speedup 1.0000x reference)
//
#include <hip/hip_runtime.h>

#define B_  4
#define D_  512
#define H_  8
#define DV_ 64
#define S_  2048
#define LDT 72              // padded LDS leading dim (bf16 elems) for the GEMM kernels

typedef __bf16 bf16;
typedef bf16  bf16x8 __attribute__((ext_vector_type(8)));
typedef bf16  bf16x4 __attribute__((ext_vector_type(4)));
typedef float f32x4  __attribute__((ext_vector_type(4)));

#define MFMA(a, b, c) __builtin_amdgcn_mfma_f32_16x16x32_bf16((a), (b), (c), 0, 0, 0)

// ---------------------------------------------------------------------------
// Kernel 1: x (B, D, S) fp32  ->  xb (B, S, D) bf16   (transpose + cast)
// ---------------------------------------------------------------------------
__global__ __launch_bounds__(256) void transpose_x(const float* __restrict__ x,
                                                   bf16* __restrict__ xb) {
    __shared__ float tile[32][33];
    const int bidx = blockIdx.x;                 // B * (D/32) * (S/32)
    const int sblk = bidx % (S_ / 32);
    const int dblk = (bidx / (S_ / 32)) % (D_ / 32);
    const int b    = bidx / ((S_ / 32) * (D_ / 32));
    const int d0 = dblk * 32, s0 = sblk * 32;
    const int tx = threadIdx.x & 31;
    const int ty = threadIdx.x >> 5;             // 0..7
    const float* xp = x + (size_t)b * D_ * S_;
#pragma unroll
    for (int i = 0; i < 32; i += 8)
        tile[ty + i][tx] = xp[(size_t)(d0 + ty + i) * S_ + s0 + tx];
    __syncthreads();
    bf16* xbp = xb + ((size_t)b * S_ + s0) * D_ + d0;
#pragma unroll
    for (int i = 0; i < 32; i += 8)
        xbp[(size_t)(ty + i) * D_ + tx] = (bf16)tile[tx][ty + i];
}

// ---------------------------------------------------------------------------
// Kernel 2: fused QKV projection GEMM.  (unchanged this round)
// ---------------------------------------------------------------------------
__global__ __launch_bounds__(256) void gemm_qkv(
    const bf16* __restrict__ A,
    const float* __restrict__ Wq, const float* __restrict__ Wk, const float* __restrict__ Wv,
    const float* __restrict__ bq, const float* __restrict__ bk, const float* __restrict__ bv,
    bf16* __restrict__ Q, bf16* __restrict__ K, bf16* __restrict__ Vt) {
    __shared__ bf16 As[128][LDT];
    __shared__ bf16 Bs[64][LDT];

    const int tid  = threadIdx.x;
    const int w    = tid >> 6, lane = tid & 63;
    const int m16  = lane & 15, quad = lane >> 4;

    const int nblk = blockIdx.x % 24;            // N = 1536 / 64
    const int mblk = blockIdx.x / 24;            // M = 8192 / 128
    const int m0 = mblk * 128;
    const int n0 = nblk * 64;
    const int proj = n0 >> 9;                    // 0:Q 1:K 2:V
    const int nr   = n0 & 511;
    const float* W    = (proj == 0) ? Wq : (proj == 1) ? Wk : Wv;
    const float* bias = (proj == 0) ? bq : (proj == 1) ? bk : bv;

    f32x4 acc[2][4];
#pragma unroll
    for (int i = 0; i < 2; ++i)
#pragma unroll
        for (int j = 0; j < 4; ++j) acc[i][j] = (f32x4){0.f, 0.f, 0.f, 0.f};

    for (int k0 = 0; k0 < D_; k0 += 64) {
        __syncthreads();
        {   // stage A tile: 128 x 64 bf16, 16B/thread/pass
            const int col = (tid & 7) * 8;
            const int row = tid >> 3;            // 0..31
#pragma unroll
            for (int p = 0; p < 4; ++p) {
                const int r = row + p * 32;
                *(bf16x8*)&As[r][col] = *(const bf16x8*)&A[(size_t)(m0 + r) * D_ + k0 + col];
            }
        }
        {   // stage B tile: 64 x 64 from fp32 W, convert to bf16
            const int col = (tid & 15) * 4;
            const int row = tid >> 4;            // 0..15
#pragma unroll
            for (int p = 0; p < 4; ++p) {
                const int r = row + p * 16;
                const float4 v = *(const float4*)&W[(size_t)(nr + r) * D_ + k0 + col];
                bf16x4 hv = {(bf16)v.x, (bf16)v.y, (bf16)v.z, (bf16)v.w};
                *(bf16x4*)&Bs[r][col] = hv;
            }
        }
        __syncthreads();
#pragma unroll
        for (int kk = 0; kk < 2; ++kk) {
            const bf16x8 a0 = *(const bf16x8*)&As[w * 32 + m16][kk * 32 + quad * 8];
            const bf16x8 a1 = *(const bf16x8*)&As[w * 32 + 16 + m16][kk * 32 + quad * 8];
#pragma unroll
            for (int nt = 0; nt < 4; ++nt) {
                const bf16x8 bfr = *(const bf16x8*)&Bs[nt * 16 + m16][kk * 32 + quad * 8];
                acc[0][nt] = MFMA(a0, bfr, acc[0][nt]);
                acc[1][nt] = MFMA(a1, bfr, acc[1][nt]);
            }
        }
    }

    // epilogue: add bias, cast bf16, scatter to Q/K/(V transposed)
#pragma unroll
    for (int mt = 0; mt < 2; ++mt)
#pragma unroll
        for (int nt = 0; nt < 4; ++nt) {
            const int n = nr + nt * 16 + m16;    // 0..511 within this projection
            const int h = n >> 6, e = n & 63;
            const float bia = bias[n];
#pragma unroll
            for (int r = 0; r < 4; ++r) {
                const int M = m0 + w * 32 + mt * 16 + quad * 4 + r;
                const int b = M >> 11, s = M & 2047;
                const bf16 hv = (bf16)(acc[mt][nt][r] + bia);
                if (proj == 0)
                    Q[(((size_t)b * H_ + h) * S_ + s) * DV_ + e] = hv;
                else if (proj == 1)
                    K[(((size_t)b * H_ + h) * S_ + s) * DV_ + e] = hv;
                else
                    Vt[(((size_t)b * H_ + h) * DV_ + e) * S_ + s] = hv;
            }
        }
}

// ---------------------------------------------------------------------------
// Kernel 3: flash attention v3 — key-split across waves, no LDS staging.
//  - Block = 64 q-rows of one (b,h); 4 waves; wave w owns keys [t0+w*32, +32).
//  - Q frags (all 64 q) persistent in regs; K/V frags loaded global->VGPR
//    (16B contiguous per lane in Kb / Vt layouts); LDS only for the wave-local
//    P roundtrip (C-layout write -> B-frag read). RS=36 => conflict-free writes.
//  - NO __syncthreads in the K-loop (DS ops within a wave are in-order).
//  - No max-subtraction softmax (scores bounded; exp(-1e30)=0 handles key mask).
//  - Per-wave partial O^T[64e][64q] + l via ones-MFMA; turn-based LDS reduce.
// ---------------------------------------------------------------------------
#define RS 36
__global__ __launch_bounds__(256, 2) void flash_attn(
    const bf16* __restrict__ Q, const bf16* __restrict__ K, const bf16* __restrict__ Vt,
    const float* __restrict__ mask, bf16* __restrict__ heads) {
    __shared__ union SMem {
        bf16 Ps[4][64][RS];                       // 18432 B, wave-local slices
        struct { float O[64][65]; float L[64]; } red;
    } sm;

    const int bidx = blockIdx.x;                 // B*H*(S/64) = 1024
    const int qblk = bidx & 31;
    const int h    = (bidx >> 5) & 7;
    const int b    = bidx >> 8;
    const int q0   = qblk * 64;

    const int tid = threadIdx.x;
    const int w = tid >> 6, lane = tid & 63;
    const int m16 = lane & 15, quad = lane >> 4;

    const bf16* Qp = Q  + ((size_t)b * H_ + h) * S_ * DV_;
    const bf16* Kp = K  + ((size_t)b * H_ + h) * S_ * DV_;
    const bf16* Vp = Vt + ((size_t)b * H_ + h) * DV_ * S_;
    const float* mp = mask + (size_t)b * S_;

    // Q A-frags for all 64 q-rows, pre-scaled by 1/sqrt(64) (exact in bf16)
    bf16x8 qf[4][2];
#pragma unroll
    for (int mt = 0; mt < 4; ++mt)
#pragma unroll
        for (int kk = 0; kk < 2; ++kk) {
            bf16x8 v = *(const bf16x8*)&Qp[(size_t)(q0 + mt * 16 + m16) * DV_ +
                                           kk * 32 + quad * 8];
#pragma unroll
            for (int i = 0; i < 8; ++i) v[i] = (bf16)((float)v[i] * 0.125f);
            qf[mt][kk] = v;
        }

    bf16x8 ones;
#pragma unroll
    for (int i = 0; i < 8; ++i) ones[i] = (bf16)1.0f;

    f32x4 o[4][4];                               // O^T[e=mt*16+quad*4+r][q=nt*16+m16]
    f32x4 lacc[4];
#pragma unroll
    for (int mt = 0; mt < 4; ++mt)
#pragma unroll
        for (int nt = 0; nt < 4; ++nt) o[mt][nt] = (f32x4){0.f, 0.f, 0.f, 0.f};
#pragma unroll
    for (int nt = 0; nt < 4; ++nt) lacc[nt] = (f32x4){0.f, 0.f, 0.f, 0.f};

    for (int t0 = 0; t0 < S_; t0 += 128) {
        const int tw = t0 + w * 32;              // this wave's 32 keys

        // K B-frags straight from global (16B contiguous per lane)
        bf16x8 kf[2][2];
#pragma unroll
        for (int nt = 0; nt < 2; ++nt)
#pragma unroll
            for (int kk = 0; kk < 2; ++kk)
                kf[nt][kk] = *(const bf16x8*)&Kp[(size_t)(tw + nt * 16 + m16) * DV_ +
                                                 kk * 32 + quad * 8];

        // scores S[64q][32t] for this wave's keys
        f32x4 sc[4][2];
#pragma unroll
        for (int mt = 0; mt < 4; ++mt)
#pragma unroll
            for (int nt = 0; nt < 2; ++nt) sc[mt][nt] = (f32x4){0.f, 0.f, 0.f, 0.f};
#pragma unroll
        for (int kk = 0; kk < 2; ++kk)
#pragma unroll
            for (int mt = 0; mt < 4; ++mt)
#pragma unroll
                for (int nt = 0; nt < 2; ++nt)
                    sc[mt][nt] = MFMA(qf[mt][kk], kf[nt][kk], sc[mt][nt]);

        // key mask + exp, write P to wave-local LDS (conflict-free scatter)
        const float mk0 = mp[tw + m16],      mk1 = mp[tw + 16 + m16];
        const float ng0 = (1.0f - mk0) * -1e30f, ng1 = (1.0f - mk1) * -1e30f;
#pragma unroll
        for (int mt = 0; mt < 4; ++mt)
#pragma unroll
            for (int r = 0; r < 4; ++r) {
                const int row = mt * 16 + quad * 4 + r;
                sm.Ps[w][row][m16]      = (bf16)__expf(sc[mt][0][r] * mk0 + ng0);
                sm.Ps[w][row][16 + m16] = (bf16)__expf(sc[mt][1][r] * mk1 + ng1);
            }

        // P B-frags back from LDS (b128), V^T A-frags from global
        bf16x8 pf[4];
#pragma unroll
        for (int nt = 0; nt < 4; ++nt)
            pf[nt] = *(const bf16x8*)&sm.Ps[w][nt * 16 + m16][quad * 8];
#pragma unroll
        for (int mt = 0; mt < 4; ++mt) {
            const bf16x8 vf = *(const bf16x8*)&Vp[(size_t)(mt * 16 + m16) * S_ +
                                                  tw + quad * 8];
#pragma unroll
            for (int nt = 0; nt < 4; ++nt) o[mt][nt] = MFMA(vf, pf[nt], o[mt][nt]);
        }
#pragma unroll
        for (int nt = 0; nt < 4; ++nt) lacc[nt] = MFMA(ones, pf[nt], lacc[nt]);
    }

    // ---- cross-wave reduction (turn-based accumulate into sm.red) ----
    __syncthreads();                             // all waves done with their Ps
#pragma unroll
    for (int ww = 0; ww < 4; ++ww) {
        if (w == ww) {
#pragma unroll
            for (int mt = 0; mt < 4; ++mt)
#pragma unroll
                for (int nt = 0; nt < 4; ++nt)
#pragma unroll
                    for (int r = 0; r < 4; ++r) {
                        float* slot = &sm.red.O[mt * 16 + quad * 4 + r][nt * 16 + m16];
                        *slot = (ww == 0) ? o[mt][nt][r] : (*slot + o[mt][nt][r]);
                    }
            if (quad == 0)
#pragma unroll
                for (int nt = 0; nt < 4; ++nt) {
                    float* ls = &sm.red.L[nt * 16 + m16];
                    *ls = (ww == 0) ? lacc[nt][0] : (*ls + lacc[nt][0]);
                }
        }
        __syncthreads();
    }

    // ---- final store: thread -> (q = tid>>2, 16-wide e-chunk = (tid&3)*16) ----
    const int ql = tid >> 2, ec = (tid & 3) * 16;
    const float l  = sm.red.L[ql];
    const float qm = mp[q0 + ql];
    const float inv = qm / l;
    bf16x8 hv[2];
#pragma unroll
    for (int c = 0; c < 2; ++c)
#pragma unroll
        for (int i = 0; i < 8; ++i)
            hv[c][i] = (bf16)(sm.red.O[ec + c * 8 + i][ql] * inv);
    bf16* dst = &heads[((size_t)b * S_ + q0 + ql) * D_ + h * DV_ + ec];
    *(bf16x8*)(dst)     = hv[0];
    *(bf16x8*)(dst + 8) = hv[1];
}

// ---------------------------------------------------------------------------
// Kernel 4: out projection. y = heads @ W0^T + b0, stored transposed (B, D, S) fp32
// ---------------------------------------------------------------------------
__global__ __launch_bounds__(256) void gemm_out(
    const bf16* __restrict__ A, const float* __restrict__ W0,
    const float* __restrict__ b0, float* __restrict__ out) {
    __shared__ bf16 As[128][LDT];
    __shared__ bf16 Bs[64][LDT];

    const int tid = threadIdx.x;
    const int w = tid >> 6, lane = tid & 63;
    const int m16 = lane & 15, quad = lane >> 4;

    const int nblk = blockIdx.x % 8;             // N = 512 / 64
    const int mblk = blockIdx.x / 8;
    const int m0 = mblk * 128, n0 = nblk * 64;

    f32x4 acc[2][4];
#pragma unroll
    for (int i = 0; i < 2; ++i)
#pragma unroll
        for (int j = 0; j < 4; ++j) acc[i][j] = (f32x4){0.f, 0.f, 0.f, 0.f};

    for (int k0 = 0; k0 < D_; k0 += 64) {
        __syncthreads();
        {
            const int col = (tid & 7) * 8;
            const int row = tid >> 3;
#pragma unroll
            for (int p = 0; p < 4; ++p) {
                const int r = row + p * 32;
                *(bf16x8*)&As[r][col] = *(const bf16x8*)&A[(size_t)(m0 + r) * D_ + k0 + col];
            }
        }
        {
            const int col = (tid & 15) * 4;
            const int row = tid >> 4;
#pragma unroll
            for (int p = 0; p < 4; ++p) {
                const int r = row + p * 16;
                const float4 v = *(const float4*)&W0[(size_t)(n0 + r) * D_ + k0 + col];
                bf16x4 hv = {(bf16)v.x, (bf16)v.y, (bf16)v.z, (bf16)v.w};
                *(bf16x4*)&Bs[r][col] = hv;
            }
        }
        __syncthreads();
#pragma unroll
        for (int kk = 0; kk < 2; ++kk) {
            const bf16x8 a0 = *(const bf16x8*)&As[w * 32 + m16][kk * 32 + quad * 8];
            const bf16x8 a1 = *(const bf16x8*)&As[w * 32 + 16 + m16][kk * 32 + quad * 8];
#pragma unroll
            for (int nt = 0; nt < 4; ++nt) {
                const bf16x8 bfr = *(const bf16x8*)&Bs[nt * 16 + m16][kk * 32 + quad * 8];
                acc[0][nt] = MFMA(a0, bfr, acc[0][nt]);
                acc[1][nt] = MFMA(a1, bfr, acc[1][nt]);
            }
        }
    }

    // epilogue: +b0, transposed store out[b][n][s], float4 along s
#pragma unroll
    for (int mt = 0; mt < 2; ++mt)
#pragma unroll
        for (int nt = 0; nt < 4; ++nt) {
            const int n  = n0 + nt * 16 + m16;
            const int Mb = m0 + w * 32 + mt * 16 + quad * 4;
            const int b  = Mb >> 11, s = Mb & 2047;
            const float bia = b0[n];
            float4 vv;
            vv.x = acc[mt][nt][0] + bia;
            vv.y = acc[mt][nt][1] + bia;
            vv.z = acc[mt][nt][2] + bia;
            vv.w = acc[mt][nt][3] + bia;
            *(float4*)&out[((size_t)b * D_ + n) * S_ + s] = vv;
        }
}

// ---------------------------------------------------------------------------
extern "C" void kernel_launch(void* const* d_in, const int* in_sizes, int n_in,
                              void* d_out, int out_size, void* d_ws, size_t ws_size,
                              hipStream_t stream) {
    const float* x    = (const float*)d_in[0];
    const float* mask = (const float*)d_in[1];
    const float* Wq   = (const float*)d_in[2];
    const float* bq   = (const float*)d_in[3];
    const float* Wk   = (const float*)d_in[4];
    const float* bk   = (const float*)d_in[5];
    const float* Wv   = (const float*)d_in[6];
    const float* bv   = (const float*)d_in[7];
    const float* W0   = (const float*)d_in[8];
    const float* b0   = (const float*)d_in[9];
    float* out = (float*)d_out;

    char* ws = (char*)d_ws;
    const size_t SEG = (size_t)B_ * S_ * D_ * sizeof(bf16);   // 8 MiB
    bf16* xb    = (bf16*)(ws);            // also reused as `heads` after gemm_qkv
    bf16* Qb    = (bf16*)(ws + SEG);
    bf16* Kb    = (bf16*)(ws + 2 * SEG);
    bf16* Vt    = (bf16*)(ws + 3 * SEG);
    bf16* heads = xb;

    transpose_x<<<dim3(B_ * (D_ / 32) * (S_ / 32)), dim3(256), 0, stream>>>(x, xb);
    gemm_qkv<<<dim3((B_ * S_ / 128) * (1536 / 64)), dim3(256), 0, stream>>>(
        xb, Wq, Wk, Wv, bq, bk, bv, Qb, Kb, Vt);
    flash_attn<<<dim3(B_ * H_ * (S_ / 64)), dim3(256), 0, stream>>>(Qb, Kb, Vt, mask, heads);
    gemm_out<<<dim3((B_ * S_ / 128) * (D_ / 64)), dim3(256), 0, stream>>>(heads, W0, b0, out);
}